// Round 3
// baseline (366.079 us; speedup 1.0000x reference)
//
#include <hip/hip_runtime.h>
#include <math.h>

#define NQ   512
#define DD   27
#define NC   10
#define KK   3
#define NTHR 256
#define TF   32                 // features per dynamic task
#define KNN_BLOCKS 512          // 2 blocks/CU resident
#define NWAVE (KNN_BLOCKS*4)    // 2048 waves
#define NWHALF (NWAVE/2)        // 1024 waves per query-half

static __device__ __forceinline__ unsigned fbits(float x){ return __float_as_uint(x); }

// K1: scale[d] = max |features[:,d]| (proven in round 2).
__global__ void k_scale(const float* __restrict__ feats, unsigned* __restrict__ scale_bits,
                        int total, int total_f4) {
  __shared__ unsigned smax[DD];
  int t = threadIdx.x;
  if (t < DD) smax[t] = 0u;
  __syncthreads();
  int gid = blockIdx.x * blockDim.x + t;
  int stride = gridDim.x * blockDim.x;       // 432*256 = 110592 = 27*4096
  const float4* f4 = (const float4*)feats;
  float m0=0.f, m1=0.f, m2=0.f, m3=0.f;
  for (int i = gid; i < total_f4; i += stride) {
    float4 v = f4[i];
    m0 = fmaxf(m0, fabsf(v.x));
    m1 = fmaxf(m1, fabsf(v.y));
    m2 = fmaxf(m2, fabsf(v.z));
    m3 = fmaxf(m3, fabsf(v.w));
  }
  int d0 = (4*gid) % DD;
  atomicMax(&smax[d0],          fbits(m0));
  atomicMax(&smax[(d0+1)%DD],   fbits(m1));
  atomicMax(&smax[(d0+2)%DD],   fbits(m2));
  atomicMax(&smax[(d0+3)%DD],   fbits(m3));
  if (gid == 0) {  // generic tail (not hit: 5.4M floats divisible by 4)
    for (int i = total_f4*4; i < total; ++i)
      atomicMax(&scale_bits[i % DD], fbits(fabsf(feats[i])));
  }
  __syncthreads();
  if (t < DD) atomicMax(&scale_bits[t], smax[t]);
}

// K2: rscale; q' = q*r^2 (folds scaling into query side); qnorm = sum((q*r)^2).
__global__ void k_prep(const float* __restrict__ queries, const unsigned* __restrict__ scale_bits,
                       float* __restrict__ rscale, float* __restrict__ qp,
                       float* __restrict__ qnorm) {
  __shared__ float rs[DD];
  int t = threadIdx.x;
  if (t < DD) {
    float s = __uint_as_float(scale_bits[t]);
    float r = (s == 0.f) ? 0.f : 1.f / s;
    rs[t] = r;
    rscale[t] = r;
  }
  __syncthreads();
  float nrm = 0.f;
  #pragma unroll
  for (int d = 0; d < DD; ++d) {
    float v = queries[t*DD + d] * rs[d];    // q*r (matches reference fs/qs rounding)
    qp[t*DD + d] = v * rs[d];               // q*r^2
    nrm = fmaf(v, v, nrm);
  }
  qnorm[t] = nrm;
}

// K2b: fnorm2[f] = sum_d (f_d * r_d)^2  — 0.8 MB, read once per f in k_knn.
__global__ void k_fnorm(const float* __restrict__ feats, const float* __restrict__ rscale,
                        float* __restrict__ fnorm2, int nfeat) {
  __shared__ float rs[DD];
  int t = threadIdx.x;
  if (t < DD) rs[t] = rscale[t];
  __syncthreads();
  int f = blockIdx.x * blockDim.x + t;
  if (f < nfeat) {
    const float* row = feats + f*DD;
    float acc = 0.f;
    #pragma unroll
    for (int d = 0; d < DD; ++d) { float v = row[d] * rs[d]; acc = fmaf(v, v, acc); }
    fnorm2[f] = acc;
  }
}

// Inner body: one feature row against 4 queries + top-3 insert (strict >, earliest idx wins).
#define FEAT_BODY(f) do {                                                   \
    const float* row_ = feats + (f)*DD;                                     \
    float fn_ = fnorm2[(f)];                                                \
    float a_[4];                                                            \
    _Pragma("unroll")                                                       \
    for (int k_ = 0; k_ < 4; ++k_) a_[k_] = fn_ * -0.5f;                    \
    _Pragma("unroll")                                                       \
    for (int d_ = 0; d_ < DD; ++d_) {                                       \
      float fv_ = row_[d_];      /* wave-uniform -> scalar load (SGPR) */   \
      _Pragma("unroll")                                                     \
      for (int k_ = 0; k_ < 4; ++k_) a_[k_] = fmaf(fv_, q[k_][d_], a_[k_]); \
    }                                                                       \
    _Pragma("unroll")                                                       \
    for (int k_ = 0; k_ < 4; ++k_) {                                        \
      float acc_ = a_[k_];                                                  \
      if (acc_ > s2[k_]) {                                                  \
        if (acc_ > s0[k_])      { s2[k_]=s1[k_];i2[k_]=i1[k_]; s1[k_]=s0[k_];i1[k_]=i0[k_]; s0[k_]=acc_;i0[k_]=(f); } \
        else if (acc_ > s1[k_]) { s2[k_]=s1[k_];i2[k_]=i1[k_]; s1[k_]=acc_;i1[k_]=(f); } \
        else                    { s2[k_]=acc_; i2[k_]=(f); }                \
      }                                                                     \
    }                                                                       \
  } while (0)

// K3: per-wave KNN. Wave = 64 lanes x 4 queries = 256 queries (one half of 512).
// Feature rows read via wave-uniform scalar loads: v_fma_f32 vD, sF, vQ, vAcc.
// No LDS, no barriers; dynamic task queue (atomic counter per query-half).
__global__ __launch_bounds__(NTHR, 2) void k_knn(
    const float* __restrict__ feats, const float* __restrict__ qp,
    const float* __restrict__ fnorm2, float* __restrict__ pd2,
    int* __restrict__ pidx, unsigned* __restrict__ ctr, int ntask, int nfeat) {
  int t = threadIdx.x;
  int lane = t & 63;
  int wid  = blockIdx.x * 4 + (t >> 6);
  int half = wid & 1;
  float q[4][DD];
  #pragma unroll
  for (int k = 0; k < 4; ++k) {
    int qq = half*256 + k*64 + lane;
    #pragma unroll
    for (int d = 0; d < DD; ++d) q[k][d] = qp[qq*DD + d];
  }
  float s0[4], s1[4], s2[4];
  int   i0[4], i1[4], i2[4];
  #pragma unroll
  for (int k = 0; k < 4; ++k) { s0[k]=s1[k]=s2[k]=-INFINITY; i0[k]=i1[k]=i2[k]=0x7fffffff; }

  for (;;) {
    unsigned c = 0;
    if (lane == 0) c = atomicAdd(&ctr[half], 1u);
    c = (unsigned)__builtin_amdgcn_readfirstlane((int)c);
    if ((int)c >= ntask) break;
    int f0 = (int)c * TF;
    #pragma unroll 2
    for (int ff = 0; ff < TF; ++ff) {
      int f = f0 + ff;
      FEAT_BODY(f);
    }
  }
  // generic tail (nfeat % TF): waves 0 (half 0) and 1 (half 1) sweep it
  int remStart = ntask * TF;
  if (wid < 2 && remStart < nfeat) {
    for (int f = remStart; f < nfeat; ++f) FEAT_BODY(f);
  }

  // coalesced partial write: [wid][qslot][3], key = -2*acc = d2 - qnorm
  #pragma unroll
  for (int k = 0; k < 4; ++k) {
    int off = (wid*256 + k*64 + lane)*3;
    pd2[off+0] = -2.f*s0[k]; pd2[off+1] = -2.f*s1[k]; pd2[off+2] = -2.f*s2[k];
    pidx[off+0] = i0[k];     pidx[off+1] = i1[k];     pidx[off+2] = i2[k];
  }
}

// insert (vv,ii) into sorted (c0<=c1<=c2), tie-break by smaller index (lax.top_k stability)
#define INS(vv, ii) do { \
  if ((vv) < c2 || ((vv) == c2 && (ii) < j2)) { \
    if ((vv) < c0 || ((vv) == c0 && (ii) < j0))      { c2=c1;j2=j1; c1=c0;j1=j0; c0=(vv);j0=(ii); } \
    else if ((vv) < c1 || ((vv) == c1 && (ii) < j1)) { c2=c1;j2=j1; c1=(vv);j1=(ii); } \
    else                                             { c2=(vv); j2=(ii); } \
  } \
} while (0)

// K4: one block per query — merge NWHALF*3 candidates, then epilogue.
__global__ __launch_bounds__(NTHR) void k_merge(
    const float* __restrict__ pd2, const int* __restrict__ pidx,
    const float* __restrict__ qnorm, const float* __restrict__ labels,
    float* __restrict__ out) {
  __shared__ float sk[NTHR*3];
  __shared__ int   si[NTHR*3];
  int q = blockIdx.x, t = threadIdx.x;
  int half = q >> 8, qs_ = q & 255;
  float c0=INFINITY, c1=INFINITY, c2=INFINITY;
  int   j0=0x7fffffff, j1=0x7fffffff, j2=0x7fffffff;
  for (int w = t; w < NWHALF; w += NTHR) {
    int wid = 2*w + half;
    int base = (wid*256 + qs_)*3;
    #pragma unroll
    for (int j = 0; j < 3; ++j) { float v = pd2[base+j]; int ix = pidx[base+j]; INS(v, ix); }
  }
  sk[t*3+0]=c0; sk[t*3+1]=c1; sk[t*3+2]=c2;
  si[t*3+0]=j0; si[t*3+1]=j1; si[t*3+2]=j2;
  __syncthreads();
  if (t < 64) {
    for (int s = 1; s < 4; ++s) {
      int b = t + s*64;
      #pragma unroll
      for (int k = 0; k < 3; ++k) { float v = sk[b*3+k]; int ix = si[b*3+k]; INS(v, ix); }
    }
    sk[t*3+0]=c0; sk[t*3+1]=c1; sk[t*3+2]=c2;
    si[t*3+0]=j0; si[t*3+1]=j1; si[t*3+2]=j2;
  }
  __syncthreads();
  if (t == 0) {
    for (int s = 1; s < 64; ++s) {
      #pragma unroll
      for (int k = 0; k < 3; ++k) { float v = sk[s*3+k]; int ix = si[s*3+k]; INS(v, ix); }
    }
    float qn = qnorm[q];
    float kd0 = sqrtf(fmaxf(c0 + qn, 0.f));
    float kd1 = sqrtf(fmaxf(c1 + qn, 0.f));
    float kd2 = sqrtf(fmaxf(c2 + qn, 0.f));
    const float* l0 = labels + (long)j0 * NC;
    const float* l1 = labels + (long)j1 * NC;
    const float* l2 = labels + (long)j2 * NC;
    float inv0 = 1.f / ((kd0 == 0.f) ? 1.f : kd0);
    float inv1 = 1.f / ((kd1 == 0.f) ? 1.f : kd1);
    float inv2 = 1.f / ((kd2 == 0.f) ? 1.f : kd2);
    float w[NC];
    #pragma unroll
    for (int cc = 0; cc < NC; ++cc)
      w[cc] = l0[cc]*inv0 + l1[cc]*inv1 + l2[cc]*inv2;
    int am = 0; float bw = w[0];
    #pragma unroll
    for (int cc = 1; cc < NC; ++cc) if (w[cc] > bw) { bw = w[cc]; am = cc; }
    float* o = out + q * (KK + NC);
    o[0] = kd0; o[1] = kd1; o[2] = kd2;
    if (kd0 == 0.f) {
      #pragma unroll
      for (int cc = 0; cc < NC; ++cc) o[3+cc] = l0[cc];
    } else {
      #pragma unroll
      for (int cc = 0; cc < NC; ++cc) o[3+cc] = (cc == am) ? 1.f : 0.f;
    }
  }
}

extern "C" void kernel_launch(void* const* d_in, const int* in_sizes, int n_in,
                              void* d_out, int out_size, void* d_ws, size_t ws_size,
                              hipStream_t stream) {
  const float* queries = (const float*)d_in[0];   // (512, 27)
  const float* feats   = (const float*)d_in[1];   // (200000, 27)
  const float* labels  = (const float*)d_in[2];   // (200000, 10)
  float* out = (float*)d_out;                     // (512, 13)
  char*  ws  = (char*)d_ws;

  int total = in_sizes[1];                         // 5,400,000
  int nfeat = total / DD;                          // 200,000

  // ws layout (all regions fully rewritten every launch; ctr zeroed by memset)
  unsigned* ctr        = (unsigned*)ws;            // 2 u32 @ 0
  unsigned* scale_bits = (unsigned*)(ws + 64);     // 27 u32
  float* rscale = (float*)(ws + 256);              // 27 f32
  float* qnorm  = (float*)(ws + 512);              // 512 f32
  float* qp     = (float*)(ws + 4096);             // 512*27 f32
  float* fnorm2 = (float*)(ws + 65536);            // 200000 f32 (800 KB)
  float* pd2    = (float*)(ws + 1048576);          // [2048][256][3] f32 (6.29 MB)
  int*   pidx   = (int*)(ws + 8388608);            // same shape (6.29 MB) -> ends 14.7 MB

  int ntask = nfeat / TF;                          // 6250 (exact for 200000)

  hipMemsetAsync(ws, 0, 256, stream);              // zero ctr + scale_bits
  k_scale<<<432, 256, 0, stream>>>(feats, scale_bits, total, total / 4);
  k_prep <<<1, NQ, 0, stream>>>(queries, scale_bits, rscale, qp, qnorm);
  k_fnorm<<<(nfeat + 255) / 256, 256, 0, stream>>>(feats, rscale, fnorm2, nfeat);
  k_knn  <<<KNN_BLOCKS, NTHR, 0, stream>>>(feats, qp, fnorm2, pd2, pidx, ctr, ntask, nfeat);
  k_merge<<<NQ, NTHR, 0, stream>>>(pd2, pidx, qnorm, labels, out);
}

// Round 4
// 261.958 us; speedup vs baseline: 1.3975x; 1.3975x over previous
//
#include <hip/hip_runtime.h>
#include <math.h>

#define NQ     512
#define DD     27
#define NC     10
#define KK     3
#define NTHR   256
#define NSLICE 320              // feature slices
#define NBLK   (NSLICE*4)       // 1280 blocks = 5 blocks/CU, fully resident
#define NCAND  (NSLICE*3)       // 960 candidates per query

static __device__ __forceinline__ unsigned fbits(float x){ return __float_as_uint(x); }

// K1: scale[d] = max |features[:,d]| (proven r2/r3).
__global__ void k_scale(const float* __restrict__ feats, unsigned* __restrict__ scale_bits,
                        int total, int total_f4) {
  __shared__ unsigned smax[DD];
  int t = threadIdx.x;
  if (t < DD) smax[t] = 0u;
  __syncthreads();
  int gid = blockIdx.x * blockDim.x + t;
  int stride = gridDim.x * blockDim.x;       // 432*256 = 110592 = 27*4096
  const float4* f4 = (const float4*)feats;
  float m0=0.f, m1=0.f, m2=0.f, m3=0.f;
  for (int i = gid; i < total_f4; i += stride) {
    float4 v = f4[i];
    m0 = fmaxf(m0, fabsf(v.x));
    m1 = fmaxf(m1, fabsf(v.y));
    m2 = fmaxf(m2, fabsf(v.z));
    m3 = fmaxf(m3, fabsf(v.w));
  }
  int d0 = (4*gid) % DD;
  atomicMax(&smax[d0],          fbits(m0));
  atomicMax(&smax[(d0+1)%DD],   fbits(m1));
  atomicMax(&smax[(d0+2)%DD],   fbits(m2));
  atomicMax(&smax[(d0+3)%DD],   fbits(m3));
  if (gid == 0) {
    for (int i = total_f4*4; i < total; ++i)
      atomicMax(&scale_bits[i % DD], fbits(fabsf(feats[i])));
  }
  __syncthreads();
  if (t < DD) atomicMax(&scale_bits[t], smax[t]);
}

// K2: rscale; q' = q*r^2 (scale folded into query side, proven r3); qnorm = sum((q*r)^2).
__global__ void k_prep(const float* __restrict__ queries, const unsigned* __restrict__ scale_bits,
                       float* __restrict__ rscale, float* __restrict__ qp,
                       float* __restrict__ qnorm) {
  __shared__ float rs[DD];
  int t = threadIdx.x;
  if (t < DD) {
    float s = __uint_as_float(scale_bits[t]);
    float r = (s == 0.f) ? 0.f : 1.f / s;
    rs[t] = r;
    rscale[t] = r;
  }
  __syncthreads();
  float nrm = 0.f;
  #pragma unroll
  for (int d = 0; d < DD; ++d) {
    float v = queries[t*DD + d] * rs[d];
    qp[t*DD + d] = v * rs[d];               // q*r^2
    nrm = fmaf(v, v, nrm);
  }
  qnorm[t] = nrm;
}

// K2b: fnorm2[f] = sum_d (f_d * r_d)^2.
__global__ void k_fnorm(const float* __restrict__ feats, const float* __restrict__ rscale,
                        float* __restrict__ fnorm2, int nfeat) {
  __shared__ float rs[DD];
  int t = threadIdx.x;
  if (t < DD) rs[t] = rscale[t];
  __syncthreads();
  int f = blockIdx.x * blockDim.x + t;
  if (f < nfeat) {
    const float* row = feats + (size_t)f*DD;
    float acc = 0.f;
    #pragma unroll
    for (int d = 0; d < DD; ++d) { float v = row[d] * rs[d]; acc = fmaf(v, v, acc); }
    fnorm2[f] = acc;
  }
}

// insert acc into descending top-3 (largest acc == smallest d2); strict > keeps earliest idx
#define TINS(acc, fi, sA, sB, sC, iA, iB, iC) do {                        \
    if ((acc) > sC) {                                                     \
      if ((acc) > sA)      { sC=sB;iC=iB; sB=sA;iB=iA; sA=(acc);iA=(fi); }\
      else if ((acc) > sB) { sC=sB;iC=iB; sB=(acc);iB=(fi); }             \
      else                 { sC=(acc); iC=(fi); }                         \
    }                                                                     \
  } while (0)

// K3: per-wave KNN, no LDS in the hot loop, no barriers, static resident partition.
// Block b: query quarter qt=b/NSLICE (queries qt*128..+127), feature slice b%NSLICE.
// Wave w takes a contiguous sub-range of the slice; feature row addresses are
// wave-uniform (w via readfirstlane) -> scalar-path loads, broadcast to 128 q/wave
// (2 queries per lane).  acc = sum_d f_d*q'_d - 0.5*fnorm2;  d2 = -2*acc + qnorm.
__global__ __launch_bounds__(NTHR, 5) void k_knn(
    const float* __restrict__ feats, const float* __restrict__ qp,
    const float* __restrict__ fnorm2, float* __restrict__ pd2v,
    int* __restrict__ pd2i, int nfeat) {
  int t = threadIdx.x;
  int lane = t & 63;
  int w = __builtin_amdgcn_readfirstlane(t >> 6);   // wave id, provably uniform
  int b = blockIdx.x;
  int qt    = b / NSLICE;                            // 0..3
  int slice = b - qt*NSLICE;                         // 0..NSLICE-1

  float q0[DD], q1[DD];
  int qa = qt*128 + lane;
  #pragma unroll
  for (int d = 0; d < DD; ++d) {
    q0[d] = qp[qa*DD + d];
    q1[d] = qp[(qa+64)*DD + d];
  }

  float s00=-INFINITY, s01=-INFINITY, s02=-INFINITY;
  float s10=-INFINITY, s11=-INFINITY, s12=-INFINITY;
  int   i00=0x7fffffff, i01=0x7fffffff, i02=0x7fffffff;
  int   i10=0x7fffffff, i11=0x7fffffff, i12=0x7fffffff;

  int S = (nfeat + NSLICE - 1) / NSLICE;             // 625
  int base = slice * S;
  int cnt = nfeat - base; if (cnt > S) cnt = S; if (cnt < 0) cnt = 0;
  int fb = base + (cnt * w) / 4;
  int fe = base + (cnt * (w+1)) / 4;

  for (int f = fb; f < fe; ++f) {
    const float* row = feats + (size_t)f * DD;       // uniform address
    float fn = fnorm2[f];                            // uniform
    float a0 = -0.5f * fn;
    float a1 = -0.5f * fn;
    #pragma unroll
    for (int d = 0; d < DD; ++d) {
      float fv = row[d];
      a0 = fmaf(fv, q0[d], a0);
      a1 = fmaf(fv, q1[d], a1);
    }
    TINS(a0, f, s00, s01, s02, i00, i01, i02);
    TINS(a1, f, s10, s11, s12, i10, i11, i12);
  }

  // intra-block merge: 4 waves x 128 query-slots x top3 -> block top3 per query
  __shared__ float sv[4][128][3];
  __shared__ int   sx[4][128][3];
  sv[w][lane][0]    = s00; sv[w][lane][1]    = s01; sv[w][lane][2]    = s02;
  sx[w][lane][0]    = i00; sx[w][lane][1]    = i01; sx[w][lane][2]    = i02;
  sv[w][lane+64][0] = s10; sv[w][lane+64][1] = s11; sv[w][lane+64][2] = s12;
  sx[w][lane+64][0] = i10; sx[w][lane+64][1] = i11; sx[w][lane+64][2] = i12;
  __syncthreads();
  if (t < 128) {
    float b0=-INFINITY, b1=-INFINITY, b2=-INFINITY;
    int   x0=0x7fffffff, x1=0x7fffffff, x2=0x7fffffff;
    #pragma unroll
    for (int ww = 0; ww < 4; ++ww) {
      #pragma unroll
      for (int j = 0; j < 3; ++j) {
        float v = sv[ww][t][j]; int ix = sx[ww][t][j];
        // descending-top3 insert with tie->smaller idx (matches lax.top_k on -dist)
        if (v > b2 || (v == b2 && ix < x2)) {
          if (v > b0 || (v == b0 && ix < x0))      { b2=b1;x2=x1; b1=b0;x1=x0; b0=v;x0=ix; }
          else if (v > b1 || (v == b1 && ix < x1)) { b2=b1;x2=x1; b1=v;x1=ix; }
          else                                     { b2=v; x2=ix; }
        }
      }
    }
    int q = qt*128 + t;
    long o = (long)q * NCAND + slice*3;
    pd2v[o+0] = -2.f*b0; pd2v[o+1] = -2.f*b1; pd2v[o+2] = -2.f*b2;   // key = d2 - qnorm
    pd2i[o+0] = x0;      pd2i[o+1] = x1;      pd2i[o+2] = x2;
  }
}

// ascending insert into (c0<=c1<=c2), tie-break smaller index
#define INS(vv, ii) do { \
  if ((vv) < c2 || ((vv) == c2 && (ii) < j2)) { \
    if ((vv) < c0 || ((vv) == c0 && (ii) < j0))      { c2=c1;j2=j1; c1=c0;j1=j0; c0=(vv);j0=(ii); } \
    else if ((vv) < c1 || ((vv) == c1 && (ii) < j1)) { c2=c1;j2=j1; c1=(vv);j1=(ii); } \
    else                                             { c2=(vv); j2=(ii); } \
  } \
} while (0)

// K4: one block per query — merge NCAND coalesced candidates, then epilogue.
__global__ __launch_bounds__(NTHR) void k_merge(
    const float* __restrict__ pd2v, const int* __restrict__ pd2i,
    const float* __restrict__ qnorm, const float* __restrict__ labels,
    float* __restrict__ out) {
  __shared__ float sk[NTHR*3];
  __shared__ int   si[NTHR*3];
  int q = blockIdx.x, t = threadIdx.x;
  float c0=INFINITY, c1=INFINITY, c2=INFINITY;
  int   j0=0x7fffffff, j1=0x7fffffff, j2=0x7fffffff;
  const float* pv = pd2v + (long)q * NCAND;
  const int*   pi = pd2i + (long)q * NCAND;
  for (int i = t; i < NCAND; i += NTHR) {
    float v = pv[i]; int ix = pi[i];
    INS(v, ix);
  }
  sk[t*3+0]=c0; sk[t*3+1]=c1; sk[t*3+2]=c2;
  si[t*3+0]=j0; si[t*3+1]=j1; si[t*3+2]=j2;
  __syncthreads();
  if (t < 64) {
    for (int s = 1; s < 4; ++s) {
      int bb = t + s*64;
      #pragma unroll
      for (int k = 0; k < 3; ++k) { float v = sk[bb*3+k]; int ix = si[bb*3+k]; INS(v, ix); }
    }
    sk[t*3+0]=c0; sk[t*3+1]=c1; sk[t*3+2]=c2;
    si[t*3+0]=j0; si[t*3+1]=j1; si[t*3+2]=j2;
  }
  __syncthreads();
  if (t == 0) {
    for (int s = 1; s < 64; ++s) {
      #pragma unroll
      for (int k = 0; k < 3; ++k) { float v = sk[s*3+k]; int ix = si[s*3+k]; INS(v, ix); }
    }
    float qn = qnorm[q];
    float kd0 = sqrtf(fmaxf(c0 + qn, 0.f));
    float kd1 = sqrtf(fmaxf(c1 + qn, 0.f));
    float kd2 = sqrtf(fmaxf(c2 + qn, 0.f));
    const float* l0 = labels + (long)j0 * NC;
    const float* l1 = labels + (long)j1 * NC;
    const float* l2 = labels + (long)j2 * NC;
    float inv0 = 1.f / ((kd0 == 0.f) ? 1.f : kd0);
    float inv1 = 1.f / ((kd1 == 0.f) ? 1.f : kd1);
    float inv2 = 1.f / ((kd2 == 0.f) ? 1.f : kd2);
    float wv[NC];
    #pragma unroll
    for (int cc = 0; cc < NC; ++cc)
      wv[cc] = l0[cc]*inv0 + l1[cc]*inv1 + l2[cc]*inv2;
    int am = 0; float bw = wv[0];
    #pragma unroll
    for (int cc = 1; cc < NC; ++cc) if (wv[cc] > bw) { bw = wv[cc]; am = cc; }
    float* o = out + q * (KK + NC);
    o[0] = kd0; o[1] = kd1; o[2] = kd2;
    if (kd0 == 0.f) {
      #pragma unroll
      for (int cc = 0; cc < NC; ++cc) o[3+cc] = l0[cc];
    } else {
      #pragma unroll
      for (int cc = 0; cc < NC; ++cc) o[3+cc] = (cc == am) ? 1.f : 0.f;
    }
  }
}

extern "C" void kernel_launch(void* const* d_in, const int* in_sizes, int n_in,
                              void* d_out, int out_size, void* d_ws, size_t ws_size,
                              hipStream_t stream) {
  const float* queries = (const float*)d_in[0];   // (512, 27)
  const float* feats   = (const float*)d_in[1];   // (200000, 27)
  const float* labels  = (const float*)d_in[2];   // (200000, 10)
  float* out = (float*)d_out;                     // (512, 13)
  char*  ws  = (char*)d_ws;

  int total = in_sizes[1];                         // 5,400,000
  int nfeat = total / DD;                          // 200,000

  unsigned* scale_bits = (unsigned*)ws;            // 27 u32 @ 0 (zeroed)
  float* rscale = (float*)(ws + 256);              // 27 f32
  float* qnorm  = (float*)(ws + 512);              // 512 f32
  float* qp     = (float*)(ws + 4096);             // 512*27 f32
  float* fnorm2 = (float*)(ws + 65536);            // 200000 f32 (800 KB)
  float* pd2v   = (float*)(ws + 1048576);          // [512][960] f32 (1.97 MB)
  int*   pd2i   = (int*)(ws + 1048576 + 2097152);  // [512][960] i32 (1.97 MB) -> ends ~5.1 MB

  hipMemsetAsync(ws, 0, 128, stream);              // zero scale_bits
  k_scale<<<432, 256, 0, stream>>>(feats, scale_bits, total, total / 4);
  k_prep <<<1, NQ, 0, stream>>>(queries, scale_bits, rscale, qp, qnorm);
  k_fnorm<<<(nfeat + 255) / 256, 256, 0, stream>>>(feats, rscale, fnorm2, nfeat);
  k_knn  <<<NBLK, NTHR, 0, stream>>>(feats, qp, fnorm2, pd2v, pd2i, nfeat);
  k_merge<<<NQ, NTHR, 0, stream>>>(pd2v, pd2i, qnorm, labels, out);
}

// Round 5
// 261.133 us; speedup vs baseline: 1.4019x; 1.0032x over previous
//
#include <hip/hip_runtime.h>
#include <math.h>

#define NQ     512
#define DD     27
#define NC     10
#define KK     3
#define NTHR   256
#define NSLICE 256              // feature slices
#define NBLK   (NSLICE*4)       // 1024 blocks = 4 blocks/CU, fully resident
#define NCAND  (NSLICE*3)       // 768 candidates per query

static __device__ __forceinline__ unsigned fbits(float x){ return __float_as_uint(x); }

// K1: scale[d] = max |features[:,d]| (proven r2-r4).
__global__ void k_scale(const float* __restrict__ feats, unsigned* __restrict__ scale_bits,
                        int total, int total_f4) {
  __shared__ unsigned smax[DD];
  int t = threadIdx.x;
  if (t < DD) smax[t] = 0u;
  __syncthreads();
  int gid = blockIdx.x * blockDim.x + t;
  int stride = gridDim.x * blockDim.x;       // 864*256 = 221184 f4 ≡ 0 mod 27
  const float4* f4 = (const float4*)feats;
  float m0=0.f, m1=0.f, m2=0.f, m3=0.f;
  for (int i = gid; i < total_f4; i += stride) {
    float4 v = f4[i];
    m0 = fmaxf(m0, fabsf(v.x));
    m1 = fmaxf(m1, fabsf(v.y));
    m2 = fmaxf(m2, fabsf(v.z));
    m3 = fmaxf(m3, fabsf(v.w));
  }
  int d0 = (4*gid) % DD;
  atomicMax(&smax[d0],          fbits(m0));
  atomicMax(&smax[(d0+1)%DD],   fbits(m1));
  atomicMax(&smax[(d0+2)%DD],   fbits(m2));
  atomicMax(&smax[(d0+3)%DD],   fbits(m3));
  if (gid == 0) {
    for (int i = total_f4*4; i < total; ++i)
      atomicMax(&scale_bits[i % DD], fbits(fabsf(feats[i])));
  }
  __syncthreads();
  if (t < DD) atomicMax(&scale_bits[t], smax[t]);
}

// K2: rscale; q' = q*r^2 (scale folded into query side); qnorm = sum((q*r)^2).
__global__ void k_prep(const float* __restrict__ queries, const unsigned* __restrict__ scale_bits,
                       float* __restrict__ rscale, float* __restrict__ qp,
                       float* __restrict__ qnorm) {
  __shared__ float rs[DD];
  int t = threadIdx.x;
  if (t < DD) {
    float s = __uint_as_float(scale_bits[t]);
    float r = (s == 0.f) ? 0.f : 1.f / s;
    rs[t] = r;
    rscale[t] = r;
  }
  __syncthreads();
  float nrm = 0.f;
  #pragma unroll
  for (int d = 0; d < DD; ++d) {
    float v = queries[t*DD + d] * rs[d];
    qp[t*DD + d] = v * rs[d];               // q*r^2
    nrm = fmaf(v, v, nrm);
  }
  qnorm[t] = nrm;
}

// K2b: fnorm2[f] = sum_d (f_d * r_d)^2.
__global__ void k_fnorm(const float* __restrict__ feats, const float* __restrict__ rscale,
                        float* __restrict__ fnorm2, int nfeat) {
  __shared__ float rs[DD];
  int t = threadIdx.x;
  if (t < DD) rs[t] = rscale[t];
  __syncthreads();
  int f = blockIdx.x * blockDim.x + t;
  if (f < nfeat) {
    const float* row = feats + (size_t)f*DD;
    float acc = 0.f;
    #pragma unroll
    for (int d = 0; d < DD; ++d) { float v = row[d] * rs[d]; acc = fmaf(v, v, acc); }
    fnorm2[f] = acc;
  }
}

// insert acc into descending top-3 (largest acc == smallest d2); strict > keeps earliest idx
#define TINS(acc, fi, sA, sB, sC, iA, iB, iC) do {                        \
    if ((acc) > sC) {                                                     \
      if ((acc) > sA)      { sC=sB;iC=iB; sB=sA;iB=iA; sA=(acc);iA=(fi); }\
      else if ((acc) > sB) { sC=sB;iC=iB; sB=(acc);iB=(fi); }             \
      else                 { sC=(acc); iC=(fi); }                         \
    }                                                                     \
  } while (0)

// declare + load one dim of both owned queries as NAMED scalars (no arrays ->
// nothing the compiler can index/alias; pinned below so it cannot re-load them)
#define DECLQ(d)  float q0_##d = qp[qa*DD + (d)]; float q1_##d = qp[(qa+64)*DD + (d)];
#define QF(d)     { float fv_ = row[d]; a0 = fmaf(fv_, q0_##d, a0); a1 = fmaf(fv_, q1_##d, a1); }

// K3: per-wave KNN, no LDS in hot loop, static resident partition (1024 blocks).
// Block b: query quarter qt=b/NSLICE (queries qt*128..+127, 2 per lane),
// feature slice b%NSLICE split across 4 waves.  Feature row address is
// wave-uniform -> one cache line per wave-load, broadcast to 128 queries.
// acc = sum_d f_d*q'_d - 0.5*fnorm2;  d2 = -2*acc + qnorm (added at merge).
__global__ __launch_bounds__(NTHR, 4) void k_knn(
    const float* __restrict__ feats, const float* __restrict__ qp,
    const float* __restrict__ fnorm2, float* __restrict__ pd2v,
    int* __restrict__ pd2i, int nfeat) {
  int t = threadIdx.x;
  int lane = t & 63;
  int w = __builtin_amdgcn_readfirstlane(t >> 6);   // wave id, provably uniform
  int b = blockIdx.x;
  int qt    = b >> 8;                                // b / NSLICE (NSLICE=256)
  int slice = b & (NSLICE-1);

  int qa = qt*128 + lane;
  DECLQ(0)  DECLQ(1)  DECLQ(2)  DECLQ(3)  DECLQ(4)  DECLQ(5)  DECLQ(6)
  DECLQ(7)  DECLQ(8)  DECLQ(9)  DECLQ(10) DECLQ(11) DECLQ(12) DECLQ(13)
  DECLQ(14) DECLQ(15) DECLQ(16) DECLQ(17) DECLQ(18) DECLQ(19) DECLQ(20)
  DECLQ(21) DECLQ(22) DECLQ(23) DECLQ(24) DECLQ(25) DECLQ(26)
  // pin: asm results are opaque -> compiler cannot rematerialize the loads
  asm volatile("" : "+v"(q0_0),"+v"(q0_1),"+v"(q0_2),"+v"(q0_3),"+v"(q0_4),
                    "+v"(q0_5),"+v"(q0_6),"+v"(q0_7),"+v"(q0_8),"+v"(q0_9),
                    "+v"(q0_10),"+v"(q0_11),"+v"(q0_12),"+v"(q0_13));
  asm volatile("" : "+v"(q0_14),"+v"(q0_15),"+v"(q0_16),"+v"(q0_17),"+v"(q0_18),
                    "+v"(q0_19),"+v"(q0_20),"+v"(q0_21),"+v"(q0_22),"+v"(q0_23),
                    "+v"(q0_24),"+v"(q0_25),"+v"(q0_26));
  asm volatile("" : "+v"(q1_0),"+v"(q1_1),"+v"(q1_2),"+v"(q1_3),"+v"(q1_4),
                    "+v"(q1_5),"+v"(q1_6),"+v"(q1_7),"+v"(q1_8),"+v"(q1_9),
                    "+v"(q1_10),"+v"(q1_11),"+v"(q1_12),"+v"(q1_13));
  asm volatile("" : "+v"(q1_14),"+v"(q1_15),"+v"(q1_16),"+v"(q1_17),"+v"(q1_18),
                    "+v"(q1_19),"+v"(q1_20),"+v"(q1_21),"+v"(q1_22),"+v"(q1_23),
                    "+v"(q1_24),"+v"(q1_25),"+v"(q1_26));

  float s00=-INFINITY, s01=-INFINITY, s02=-INFINITY;
  float s10=-INFINITY, s11=-INFINITY, s12=-INFINITY;
  int   i00=0x7fffffff, i01=0x7fffffff, i02=0x7fffffff;
  int   i10=0x7fffffff, i11=0x7fffffff, i12=0x7fffffff;

  int S = (nfeat + NSLICE - 1) / NSLICE;             // 782
  int base = slice * S;
  int cnt = nfeat - base; if (cnt > S) cnt = S; if (cnt < 0) cnt = 0;
  int fb = base + (cnt * w) / 4;
  int fe = base + (cnt * (w+1)) / 4;

  #pragma unroll 2
  for (int f = fb; f < fe; ++f) {
    const float* row = feats + (size_t)f * DD;       // wave-uniform address
    float fn = fnorm2[f];                            // wave-uniform
    float a0 = -0.5f * fn;
    float a1 = -0.5f * fn;
    QF(0)  QF(1)  QF(2)  QF(3)  QF(4)  QF(5)  QF(6)  QF(7)  QF(8)
    QF(9)  QF(10) QF(11) QF(12) QF(13) QF(14) QF(15) QF(16) QF(17)
    QF(18) QF(19) QF(20) QF(21) QF(22) QF(23) QF(24) QF(25) QF(26)
    TINS(a0, f, s00, s01, s02, i00, i01, i02);
    TINS(a1, f, s10, s11, s12, i10, i11, i12);
  }

  // intra-block merge: 4 waves x 128 query-slots x top3 -> block top3 per query
  __shared__ float sv[4][128][3];
  __shared__ int   sx[4][128][3];
  sv[w][lane][0]    = s00; sv[w][lane][1]    = s01; sv[w][lane][2]    = s02;
  sx[w][lane][0]    = i00; sx[w][lane][1]    = i01; sx[w][lane][2]    = i02;
  sv[w][lane+64][0] = s10; sv[w][lane+64][1] = s11; sv[w][lane+64][2] = s12;
  sx[w][lane+64][0] = i10; sx[w][lane+64][1] = i11; sx[w][lane+64][2] = i12;
  __syncthreads();
  if (t < 128) {
    float b0=-INFINITY, b1=-INFINITY, b2=-INFINITY;
    int   x0=0x7fffffff, x1=0x7fffffff, x2=0x7fffffff;
    #pragma unroll
    for (int ww = 0; ww < 4; ++ww) {
      #pragma unroll
      for (int j = 0; j < 3; ++j) {
        float v = sv[ww][t][j]; int ix = sx[ww][t][j];
        if (v > b2 || (v == b2 && ix < x2)) {
          if (v > b0 || (v == b0 && ix < x0))      { b2=b1;x2=x1; b1=b0;x1=x0; b0=v;x0=ix; }
          else if (v > b1 || (v == b1 && ix < x1)) { b2=b1;x2=x1; b1=v;x1=ix; }
          else                                     { b2=v; x2=ix; }
        }
      }
    }
    int q = qt*128 + t;
    long o = (long)q * NCAND + slice*3;
    pd2v[o+0] = -2.f*b0; pd2v[o+1] = -2.f*b1; pd2v[o+2] = -2.f*b2;   // key = d2 - qnorm
    pd2i[o+0] = x0;      pd2i[o+1] = x1;      pd2i[o+2] = x2;
  }
}

// ascending insert into (c0<=c1<=c2), tie-break smaller index
#define INS(vv, ii) do { \
  if ((vv) < c2 || ((vv) == c2 && (ii) < j2)) { \
    if ((vv) < c0 || ((vv) == c0 && (ii) < j0))      { c2=c1;j2=j1; c1=c0;j1=j0; c0=(vv);j0=(ii); } \
    else if ((vv) < c1 || ((vv) == c1 && (ii) < j1)) { c2=c1;j2=j1; c1=(vv);j1=(ii); } \
    else                                             { c2=(vv); j2=(ii); } \
  } \
} while (0)

// K4: one block per query — merge NCAND coalesced candidates, then epilogue.
__global__ __launch_bounds__(NTHR) void k_merge(
    const float* __restrict__ pd2v, const int* __restrict__ pd2i,
    const float* __restrict__ qnorm, const float* __restrict__ labels,
    float* __restrict__ out) {
  __shared__ float sk[NTHR*3];
  __shared__ int   si[NTHR*3];
  int q = blockIdx.x, t = threadIdx.x;
  float c0=INFINITY, c1=INFINITY, c2=INFINITY;
  int   j0=0x7fffffff, j1=0x7fffffff, j2=0x7fffffff;
  const float* pv = pd2v + (long)q * NCAND;
  const int*   pi = pd2i + (long)q * NCAND;
  for (int i = t; i < NCAND; i += NTHR) {
    float v = pv[i]; int ix = pi[i];
    INS(v, ix);
  }
  sk[t*3+0]=c0; sk[t*3+1]=c1; sk[t*3+2]=c2;
  si[t*3+0]=j0; si[t*3+1]=j1; si[t*3+2]=j2;
  __syncthreads();
  if (t < 64) {
    for (int s = 1; s < 4; ++s) {
      int bb = t + s*64;
      #pragma unroll
      for (int k = 0; k < 3; ++k) { float v = sk[bb*3+k]; int ix = si[bb*3+k]; INS(v, ix); }
    }
    sk[t*3+0]=c0; sk[t*3+1]=c1; sk[t*3+2]=c2;
    si[t*3+0]=j0; si[t*3+1]=j1; si[t*3+2]=j2;
  }
  __syncthreads();
  if (t == 0) {
    for (int s = 1; s < 64; ++s) {
      #pragma unroll
      for (int k = 0; k < 3; ++k) { float v = sk[s*3+k]; int ix = si[s*3+k]; INS(v, ix); }
    }
    float qn = qnorm[q];
    float kd0 = sqrtf(fmaxf(c0 + qn, 0.f));
    float kd1 = sqrtf(fmaxf(c1 + qn, 0.f));
    float kd2 = sqrtf(fmaxf(c2 + qn, 0.f));
    const float* l0 = labels + (long)j0 * NC;
    const float* l1 = labels + (long)j1 * NC;
    const float* l2 = labels + (long)j2 * NC;
    float inv0 = 1.f / ((kd0 == 0.f) ? 1.f : kd0);
    float inv1 = 1.f / ((kd1 == 0.f) ? 1.f : kd1);
    float inv2 = 1.f / ((kd2 == 0.f) ? 1.f : kd2);
    float wv[NC];
    #pragma unroll
    for (int cc = 0; cc < NC; ++cc)
      wv[cc] = l0[cc]*inv0 + l1[cc]*inv1 + l2[cc]*inv2;
    int am = 0; float bw = wv[0];
    #pragma unroll
    for (int cc = 1; cc < NC; ++cc) if (wv[cc] > bw) { bw = wv[cc]; am = cc; }
    float* o = out + q * (KK + NC);
    o[0] = kd0; o[1] = kd1; o[2] = kd2;
    if (kd0 == 0.f) {
      #pragma unroll
      for (int cc = 0; cc < NC; ++cc) o[3+cc] = l0[cc];
    } else {
      #pragma unroll
      for (int cc = 0; cc < NC; ++cc) o[3+cc] = (cc == am) ? 1.f : 0.f;
    }
  }
}

extern "C" void kernel_launch(void* const* d_in, const int* in_sizes, int n_in,
                              void* d_out, int out_size, void* d_ws, size_t ws_size,
                              hipStream_t stream) {
  const float* queries = (const float*)d_in[0];   // (512, 27)
  const float* feats   = (const float*)d_in[1];   // (200000, 27)
  const float* labels  = (const float*)d_in[2];   // (200000, 10)
  float* out = (float*)d_out;                     // (512, 13)
  char*  ws  = (char*)d_ws;

  int total = in_sizes[1];                         // 5,400,000
  int nfeat = total / DD;                          // 200,000

  unsigned* scale_bits = (unsigned*)ws;            // 27 u32 @ 0 (zeroed)
  float* rscale = (float*)(ws + 256);              // 27 f32
  float* qnorm  = (float*)(ws + 512);              // 512 f32
  float* qp     = (float*)(ws + 4096);             // 512*27 f32
  float* fnorm2 = (float*)(ws + 65536);            // 200000 f32 (800 KB)
  float* pd2v   = (float*)(ws + 1048576);          // [512][768] f32 (1.57 MB)
  int*   pd2i   = (int*)(ws + 1048576 + 2097152);  // [512][768] i32 (1.57 MB)

  hipMemsetAsync(ws, 0, 128, stream);              // zero scale_bits
  k_scale<<<864, 256, 0, stream>>>(feats, scale_bits, total, total / 4);
  k_prep <<<1, NQ, 0, stream>>>(queries, scale_bits, rscale, qp, qnorm);
  k_fnorm<<<(nfeat + 255) / 256, 256, 0, stream>>>(feats, rscale, fnorm2, nfeat);
  k_knn  <<<NBLK, NTHR, 0, stream>>>(feats, qp, fnorm2, pd2v, pd2i, nfeat);
  k_merge<<<NQ, NTHR, 0, stream>>>(pd2v, pd2i, qnorm, labels, out);
}

// Round 6
// 257.480 us; speedup vs baseline: 1.4218x; 1.0142x over previous
//
#include <hip/hip_runtime.h>
#include <math.h>

#define NQ     512
#define DD     27
#define NC     10
#define KK     3
#define NTHR   256
#define NSLICE 256              // feature slices
#define NBLK   (NSLICE*4)       // 1024 blocks = 4 blocks/CU, fully resident
#define NCAND  (NSLICE*3)       // 768 candidates per query

static __device__ __forceinline__ unsigned fbits(float x){ return __float_as_uint(x); }

// K1: scale[d] = max |features[:,d]| (proven r2-r5).
__global__ void k_scale(const float* __restrict__ feats, unsigned* __restrict__ scale_bits,
                        int total, int total_f4) {
  __shared__ unsigned smax[DD];
  int t = threadIdx.x;
  if (t < DD) smax[t] = 0u;
  __syncthreads();
  int gid = blockIdx.x * blockDim.x + t;
  int stride = gridDim.x * blockDim.x;       // 864*256 = 221184 f4 ≡ 0 mod 27
  const float4* f4 = (const float4*)feats;
  float m0=0.f, m1=0.f, m2=0.f, m3=0.f;
  for (int i = gid; i < total_f4; i += stride) {
    float4 v = f4[i];
    m0 = fmaxf(m0, fabsf(v.x));
    m1 = fmaxf(m1, fabsf(v.y));
    m2 = fmaxf(m2, fabsf(v.z));
    m3 = fmaxf(m3, fabsf(v.w));
  }
  int d0 = (4*gid) % DD;
  atomicMax(&smax[d0],          fbits(m0));
  atomicMax(&smax[(d0+1)%DD],   fbits(m1));
  atomicMax(&smax[(d0+2)%DD],   fbits(m2));
  atomicMax(&smax[(d0+3)%DD],   fbits(m3));
  if (gid == 0) {
    for (int i = total_f4*4; i < total; ++i)
      atomicMax(&scale_bits[i % DD], fbits(fabsf(feats[i])));
  }
  __syncthreads();
  if (t < DD) atomicMax(&scale_bits[t], smax[t]);
}

// K2 (fused prep+fnorm): every block derives rs[] locally from scale_bits;
// all blocks compute fnorm2 for their features; block 0 additionally preps
// qp (q*r^2) and qnorm.  One dispatch instead of two.
__global__ void k_prepfn(const float* __restrict__ queries, const float* __restrict__ feats,
                         const unsigned* __restrict__ scale_bits, float* __restrict__ qp,
                         float* __restrict__ qnorm, float* __restrict__ fnorm2, int nfeat) {
  __shared__ float rs[DD];
  int t = threadIdx.x;
  if (t < DD) {
    float s = __uint_as_float(scale_bits[t]);
    rs[t] = (s == 0.f) ? 0.f : 1.f / s;
  }
  __syncthreads();
  int f = blockIdx.x * blockDim.x + t;
  if (f < nfeat) {
    const float* row = feats + (size_t)f*DD;
    float acc = 0.f;
    #pragma unroll
    for (int d = 0; d < DD; ++d) { float v = row[d] * rs[d]; acc = fmaf(v, v, acc); }
    fnorm2[f] = acc;
  }
  if (blockIdx.x == 0) {
    for (int qq = t; qq < NQ; qq += NTHR) {
      float nrm = 0.f;
      #pragma unroll
      for (int d = 0; d < DD; ++d) {
        float v = queries[qq*DD + d] * rs[d];   // q*r (reference rounding)
        qp[qq*DD + d] = v * rs[d];              // q*r^2
        nrm = fmaf(v, v, nrm);
      }
      qnorm[qq] = nrm;
    }
  }
}

// insert acc into descending top-3 (largest acc == smallest d2); strict > keeps earliest idx
#define TINS(acc, fi, sA, sB, sC, iA, iB, iC) do {                        \
    if ((acc) > sC) {                                                     \
      if ((acc) > sA)      { sC=sB;iC=iB; sB=sA;iB=iA; sA=(acc);iA=(fi); }\
      else if ((acc) > sB) { sC=sB;iC=iB; sB=(acc);iB=(fi); }             \
      else                 { sC=(acc); iC=(fi); }                         \
    }                                                                     \
  } while (0)

// declare + load one dim of both owned queries as NAMED scalars; pinned via asm
#define DECLQ(d)  float q0_##d = qp[qa*DD + (d)]; float q1_##d = qp[(qa+64)*DD + (d)];
#define QF(d)     { float fv_ = row[d]; a0 = fmaf(fv_, q0_##d, a0); a1 = fmaf(fv_, q1_##d, a1); }

// K3: per-wave KNN, no LDS in hot loop, static resident partition (1024 blocks).
// amdgpu_waves_per_eu(4,4): tells the scheduler EXACTLY 4 waves/EU run (grid is
// 4 blocks/CU resident), so it must not target higher occupancy -> the 54
// query floats can be register-allocated instead of remat/reloaded (r4/r5
// pathology: VGPR_Count 36-40 vs 54 live values needed).
__global__ __launch_bounds__(NTHR)
__attribute__((amdgpu_waves_per_eu(4, 4)))
void k_knn(
    const float* __restrict__ feats, const float* __restrict__ qp,
    const float* __restrict__ fnorm2, float* __restrict__ pd2v,
    int* __restrict__ pd2i, int nfeat) {
  int t = threadIdx.x;
  int lane = t & 63;
  int w = __builtin_amdgcn_readfirstlane(t >> 6);   // wave id, provably uniform
  int b = blockIdx.x;
  int qt    = b >> 8;                                // b / NSLICE (NSLICE=256)
  int slice = b & (NSLICE-1);

  int qa = qt*128 + lane;
  DECLQ(0)  DECLQ(1)  DECLQ(2)  DECLQ(3)  DECLQ(4)  DECLQ(5)  DECLQ(6)
  DECLQ(7)  DECLQ(8)  DECLQ(9)  DECLQ(10) DECLQ(11) DECLQ(12) DECLQ(13)
  DECLQ(14) DECLQ(15) DECLQ(16) DECLQ(17) DECLQ(18) DECLQ(19) DECLQ(20)
  DECLQ(21) DECLQ(22) DECLQ(23) DECLQ(24) DECLQ(25) DECLQ(26)
  // pin: asm results are opaque -> compiler cannot rematerialize the loads
  asm volatile("" : "+v"(q0_0),"+v"(q0_1),"+v"(q0_2),"+v"(q0_3),"+v"(q0_4),
                    "+v"(q0_5),"+v"(q0_6),"+v"(q0_7),"+v"(q0_8),"+v"(q0_9),
                    "+v"(q0_10),"+v"(q0_11),"+v"(q0_12),"+v"(q0_13));
  asm volatile("" : "+v"(q0_14),"+v"(q0_15),"+v"(q0_16),"+v"(q0_17),"+v"(q0_18),
                    "+v"(q0_19),"+v"(q0_20),"+v"(q0_21),"+v"(q0_22),"+v"(q0_23),
                    "+v"(q0_24),"+v"(q0_25),"+v"(q0_26));
  asm volatile("" : "+v"(q1_0),"+v"(q1_1),"+v"(q1_2),"+v"(q1_3),"+v"(q1_4),
                    "+v"(q1_5),"+v"(q1_6),"+v"(q1_7),"+v"(q1_8),"+v"(q1_9),
                    "+v"(q1_10),"+v"(q1_11),"+v"(q1_12),"+v"(q1_13));
  asm volatile("" : "+v"(q1_14),"+v"(q1_15),"+v"(q1_16),"+v"(q1_17),"+v"(q1_18),
                    "+v"(q1_19),"+v"(q1_20),"+v"(q1_21),"+v"(q1_22),"+v"(q1_23),
                    "+v"(q1_24),"+v"(q1_25),"+v"(q1_26));

  float s00=-INFINITY, s01=-INFINITY, s02=-INFINITY;
  float s10=-INFINITY, s11=-INFINITY, s12=-INFINITY;
  int   i00=0x7fffffff, i01=0x7fffffff, i02=0x7fffffff;
  int   i10=0x7fffffff, i11=0x7fffffff, i12=0x7fffffff;

  int S = (nfeat + NSLICE - 1) / NSLICE;             // 782
  int base = slice * S;
  int cnt = nfeat - base; if (cnt > S) cnt = S; if (cnt < 0) cnt = 0;
  int fb = base + (cnt * w) / 4;
  int fe = base + (cnt * (w+1)) / 4;

  #pragma unroll 2
  for (int f = fb; f < fe; ++f) {
    const float* row = feats + (size_t)f * DD;       // wave-uniform address
    float fn = fnorm2[f];                            // wave-uniform
    float a0 = -0.5f * fn;
    float a1 = -0.5f * fn;
    QF(0)  QF(1)  QF(2)  QF(3)  QF(4)  QF(5)  QF(6)  QF(7)  QF(8)
    QF(9)  QF(10) QF(11) QF(12) QF(13) QF(14) QF(15) QF(16) QF(17)
    QF(18) QF(19) QF(20) QF(21) QF(22) QF(23) QF(24) QF(25) QF(26)
    TINS(a0, f, s00, s01, s02, i00, i01, i02);
    TINS(a1, f, s10, s11, s12, i10, i11, i12);
  }

  // intra-block merge: 4 waves x 128 query-slots x top3 -> block top3 per query
  __shared__ float sv[4][128][3];
  __shared__ int   sx[4][128][3];
  sv[w][lane][0]    = s00; sv[w][lane][1]    = s01; sv[w][lane][2]    = s02;
  sx[w][lane][0]    = i00; sx[w][lane][1]    = i01; sx[w][lane][2]    = i02;
  sv[w][lane+64][0] = s10; sv[w][lane+64][1] = s11; sv[w][lane+64][2] = s12;
  sx[w][lane+64][0] = i10; sx[w][lane+64][1] = i11; sx[w][lane+64][2] = i12;
  __syncthreads();
  if (t < 128) {
    float b0=-INFINITY, b1=-INFINITY, b2=-INFINITY;
    int   x0=0x7fffffff, x1=0x7fffffff, x2=0x7fffffff;
    #pragma unroll
    for (int ww = 0; ww < 4; ++ww) {
      #pragma unroll
      for (int j = 0; j < 3; ++j) {
        float v = sv[ww][t][j]; int ix = sx[ww][t][j];
        if (v > b2 || (v == b2 && ix < x2)) {
          if (v > b0 || (v == b0 && ix < x0))      { b2=b1;x2=x1; b1=b0;x1=x0; b0=v;x0=ix; }
          else if (v > b1 || (v == b1 && ix < x1)) { b2=b1;x2=x1; b1=v;x1=ix; }
          else                                     { b2=v; x2=ix; }
        }
      }
    }
    int q = qt*128 + t;
    long o = (long)q * NCAND + slice*3;
    pd2v[o+0] = -2.f*b0; pd2v[o+1] = -2.f*b1; pd2v[o+2] = -2.f*b2;   // key = d2 - qnorm
    pd2i[o+0] = x0;      pd2i[o+1] = x1;      pd2i[o+2] = x2;
  }
}

// ascending insert into (c0<=c1<=c2), tie-break smaller index
#define INS(vv, ii) do { \
  if ((vv) < c2 || ((vv) == c2 && (ii) < j2)) { \
    if ((vv) < c0 || ((vv) == c0 && (ii) < j0))      { c2=c1;j2=j1; c1=c0;j1=j0; c0=(vv);j0=(ii); } \
    else if ((vv) < c1 || ((vv) == c1 && (ii) < j1)) { c2=c1;j2=j1; c1=(vv);j1=(ii); } \
    else                                             { c2=(vv); j2=(ii); } \
  } \
} while (0)

// K4: one block per query — merge NCAND coalesced candidates, then epilogue.
__global__ __launch_bounds__(NTHR) void k_merge(
    const float* __restrict__ pd2v, const int* __restrict__ pd2i,
    const float* __restrict__ qnorm, const float* __restrict__ labels,
    float* __restrict__ out) {
  __shared__ float sk[NTHR*3];
  __shared__ int   si[NTHR*3];
  int q = blockIdx.x, t = threadIdx.x;
  float c0=INFINITY, c1=INFINITY, c2=INFINITY;
  int   j0=0x7fffffff, j1=0x7fffffff, j2=0x7fffffff;
  const float* pv = pd2v + (long)q * NCAND;
  const int*   pi = pd2i + (long)q * NCAND;
  for (int i = t; i < NCAND; i += NTHR) {
    float v = pv[i]; int ix = pi[i];
    INS(v, ix);
  }
  sk[t*3+0]=c0; sk[t*3+1]=c1; sk[t*3+2]=c2;
  si[t*3+0]=j0; si[t*3+1]=j1; si[t*3+2]=j2;
  __syncthreads();
  if (t < 64) {
    for (int s = 1; s < 4; ++s) {
      int bb = t + s*64;
      #pragma unroll
      for (int k = 0; k < 3; ++k) { float v = sk[bb*3+k]; int ix = si[bb*3+k]; INS(v, ix); }
    }
    sk[t*3+0]=c0; sk[t*3+1]=c1; sk[t*3+2]=c2;
    si[t*3+0]=j0; si[t*3+1]=j1; si[t*3+2]=j2;
  }
  __syncthreads();
  if (t == 0) {
    for (int s = 1; s < 64; ++s) {
      #pragma unroll
      for (int k = 0; k < 3; ++k) { float v = sk[s*3+k]; int ix = si[s*3+k]; INS(v, ix); }
    }
    float qn = qnorm[q];
    float kd0 = sqrtf(fmaxf(c0 + qn, 0.f));
    float kd1 = sqrtf(fmaxf(c1 + qn, 0.f));
    float kd2 = sqrtf(fmaxf(c2 + qn, 0.f));
    const float* l0 = labels + (long)j0 * NC;
    const float* l1 = labels + (long)j1 * NC;
    const float* l2 = labels + (long)j2 * NC;
    float inv0 = 1.f / ((kd0 == 0.f) ? 1.f : kd0);
    float inv1 = 1.f / ((kd1 == 0.f) ? 1.f : kd1);
    float inv2 = 1.f / ((kd2 == 0.f) ? 1.f : kd2);
    float wv[NC];
    #pragma unroll
    for (int cc = 0; cc < NC; ++cc)
      wv[cc] = l0[cc]*inv0 + l1[cc]*inv1 + l2[cc]*inv2;
    int am = 0; float bw = wv[0];
    #pragma unroll
    for (int cc = 1; cc < NC; ++cc) if (wv[cc] > bw) { bw = wv[cc]; am = cc; }
    float* o = out + q * (KK + NC);
    o[0] = kd0; o[1] = kd1; o[2] = kd2;
    if (kd0 == 0.f) {
      #pragma unroll
      for (int cc = 0; cc < NC; ++cc) o[3+cc] = l0[cc];
    } else {
      #pragma unroll
      for (int cc = 0; cc < NC; ++cc) o[3+cc] = (cc == am) ? 1.f : 0.f;
    }
  }
}

extern "C" void kernel_launch(void* const* d_in, const int* in_sizes, int n_in,
                              void* d_out, int out_size, void* d_ws, size_t ws_size,
                              hipStream_t stream) {
  const float* queries = (const float*)d_in[0];   // (512, 27)
  const float* feats   = (const float*)d_in[1];   // (200000, 27)
  const float* labels  = (const float*)d_in[2];   // (200000, 10)
  float* out = (float*)d_out;                     // (512, 13)
  char*  ws  = (char*)d_ws;

  int total = in_sizes[1];                         // 5,400,000
  int nfeat = total / DD;                          // 200,000

  unsigned* scale_bits = (unsigned*)ws;            // 27 u32 @ 0 (zeroed)
  float* qnorm  = (float*)(ws + 512);              // 512 f32
  float* qp     = (float*)(ws + 4096);             // 512*27 f32
  float* fnorm2 = (float*)(ws + 65536);            // 200000 f32 (800 KB)
  float* pd2v   = (float*)(ws + 1048576);          // [512][768] f32 (1.57 MB)
  int*   pd2i   = (int*)(ws + 1048576 + 2097152);  // [512][768] i32 (1.57 MB)

  hipMemsetAsync(ws, 0, 128, stream);              // zero scale_bits
  k_scale<<<864, 256, 0, stream>>>(feats, scale_bits, total, total / 4);
  k_prepfn<<<(nfeat + 255) / 256, 256, 0, stream>>>(queries, feats, scale_bits,
                                                    qp, qnorm, fnorm2, nfeat);
  k_knn  <<<NBLK, NTHR, 0, stream>>>(feats, qp, fnorm2, pd2v, pd2i, nfeat);
  k_merge<<<NQ, NTHR, 0, stream>>>(pd2v, pd2i, qnorm, labels, out);
}